// Round 7
// baseline (229.563 us; speedup 1.0000x reference)
//
#include <hip/hip_runtime.h>
#include <math.h>

#define D        128
#define KCODES   2048
#define NPTS     32768
#define LO_SCALE 4096.0f
// exp2-domain: s2 = (2*dot - e^2) * log2e / T
#define C1       3.205988979753252f          // 2*log2e/T
#define C2       (C1 / LO_SCALE)
#define ESQ_SCALE 1.602994489876626f         // log2e/T

#define A_CSLICES 4
#define A_CODES   512                        // codes per slice
#define A_NCH     (A_CODES / 32)             // 16 chunks of 32 codes

// swizzle: logical 16B-group G of row r stored at slot (G ^ r) & 15
#define SW(G, r)  (((G) ^ (r)) & 15)

typedef _Float16 half8 __attribute__((ext_vector_type(8)));
typedef float    f32x4 __attribute__((ext_vector_type(4)));

// ---------------------------------------------------------------------------
// Prep (fused): fp16 hi/lo split of embed AND x (lo pre-scaled by 4096) into
// XOR-swizzled rows; e_sqt; zero classacc. 4 threads per row.
// ---------------------------------------------------------------------------
__device__ __forceinline__ void split_row_part(const float* __restrict__ src,
                                               _Float16* __restrict__ hi_row,
                                               _Float16* __restrict__ lo_row,
                                               int part, int rkey, float* ss) {
    #pragma unroll
    for (int g = 0; g < 4; ++g) {
        const int G = part * 4 + g;
        half8 h, l;
        float s = 0.0f;
        #pragma unroll
        for (int j = 0; j < 8; ++j) {
            float v = src[g * 8 + j];
            _Float16 hh = (_Float16)v;
            h[j] = hh;
            l[j] = (_Float16)((v - (float)hh) * LO_SCALE);
            s += v * v;
        }
        *ss += s;
        const int slot = SW(G, rkey);
        *(half8*)(hi_row + slot * 8) = h;
        *(half8*)(lo_row + slot * 8) = l;
    }
}

__global__ void prep_kernel(const float* __restrict__ embed, const float* __restrict__ x,
                            float* __restrict__ e_sqt,
                            _Float16* __restrict__ ehi, _Float16* __restrict__ elo,
                            _Float16* __restrict__ xhi, _Float16* __restrict__ xlo,
                            float* __restrict__ cacc) {
    const int b = blockIdx.x;
    const int tid = threadIdx.x;
    const int part = tid & 3;
    float ss = 0.0f;
    if (b < KCODES / 64) {
        const int row = b * 64 + (tid >> 2);
        split_row_part(embed + (size_t)row * D + part * 32,
                       ehi + (size_t)row * D, elo + (size_t)row * D, part, row & 15, &ss);
        ss += __shfl_xor(ss, 1, 64);
        ss += __shfl_xor(ss, 2, 64);
        if (part == 0) e_sqt[row] = ss * ESQ_SCALE;
        if (part == 1) cacc[row] = 0.0f;
    } else {
        const int row = (b - KCODES / 64) * 64 + (tid >> 2);
        split_row_part(x + (size_t)row * D + part * 32,
                       xhi + (size_t)row * D, xlo + (size_t)row * D, part, row & 15, &ss);
    }
}

// async DMA of one 32-row chunk (8 rows/wave, 256 B/row) into LDS
__device__ __forceinline__ void dma32(const _Float16* __restrict__ g_base,
                                      _Float16* lds_base, int row0, int w, int lane) {
    const char* src = (const char*)g_base + (size_t)(row0 + 8 * w) * 256 + lane * 16;
    char* dst = (char*)lds_base + 8 * w * 256;
    #pragma unroll
    for (int i = 0; i < 2; ++i) {
        __builtin_amdgcn_global_load_lds(
            (const __attribute__((address_space(1))) unsigned int*)(src + i * 1024),
            (__attribute__((address_space(3))) unsigned int*)(dst + i * 1024),
            16, 0, 0);
    }
}

// load this lane's resident A fragments (32 points, swizzled hi/lo)
__device__ __forceinline__ void load_a(const _Float16* __restrict__ xhi_g,
                                       const _Float16* __restrict__ xlo_g,
                                       int p0w, int col, int quad,
                                       half8 ahi[2][4], half8 alo[2][4]) {
    #pragma unroll
    for (int pt = 0; pt < 2; ++pt) {
        const int pr = p0w + pt * 16 + col;          // pr & 15 == col
        #pragma unroll
        for (int kk = 0; kk < 4; ++kk) {
            const int slot = SW(kk * 4 + quad, col);
            ahi[pt][kk] = *(const half8*)(xhi_g + (size_t)pr * D + slot * 8);
            alo[pt][kk] = *(const half8*)(xlo_g + (size_t)pr * D + slot * 8);
        }
    }
}

// ---------------------------------------------------------------------------
// Sweep A: point-resident (32 pts/wave), codes stream via dbuf LDS DMA.
// Softmax/argmax state in registers, flushed once. Partials [4][NPTS].
// ---------------------------------------------------------------------------
__global__ __launch_bounds__(256, 4)
void sweepA_kernel(const _Float16* __restrict__ xhi_g, const _Float16* __restrict__ xlo_g,
                   const _Float16* __restrict__ ehi_g, const _Float16* __restrict__ elo_g,
                   const float* __restrict__ e_sqt_g,
                   float* __restrict__ pm, float* __restrict__ pl, int* __restrict__ pidx) {
    __shared__ _Float16 EHI[2][32 * D];   // 2 x 8 KB
    __shared__ _Float16 ELO[2][32 * D];   // 2 x 8 KB
    __shared__ float esq_s[A_CODES];      // 2 KB

    const int tid  = threadIdx.x;
    const int w    = tid >> 6;
    const int lane = tid & 63;
    const int col  = lane & 15;
    const int quad = lane >> 4;
    const int c0   = blockIdx.y * A_CODES;
    const int p0w  = blockIdx.x * 128 + w * 32;

    dma32(ehi_g, EHI[0], c0, w, lane);
    dma32(elo_g, ELO[0], c0, w, lane);
    for (int i = tid; i < A_CODES; i += 256) esq_s[i] = e_sqt_g[c0 + i];

    half8 ahi[2][4], alo[2][4];
    load_a(xhi_g, xlo_g, p0w, col, quad, ahi, alo);

    float lrun[2][4], bv[2][4];
    int   bi[2][4];
    #pragma unroll
    for (int pt = 0; pt < 2; ++pt)
        #pragma unroll
        for (int r = 0; r < 4; ++r) { lrun[pt][r] = 0.f; bv[pt][r] = -INFINITY; bi[pt][r] = 0; }

    __syncthreads();   // chunk0 DMA + esq ready

    for (int ch = 0; ch < A_NCH; ++ch) {
        const int cur = ch & 1;
        if (ch + 1 < A_NCH) {
            dma32(ehi_g, EHI[cur ^ 1], c0 + (ch + 1) * 32, w, lane);
            dma32(elo_g, ELO[cur ^ 1], c0 + (ch + 1) * 32, w, lane);
        }
        const _Float16* eh = EHI[cur];
        const _Float16* el = ELO[cur];

        #pragma unroll
        for (int ct = 0; ct < 2; ++ct) {
            f32x4 chh[2], cx[2];
            #pragma unroll
            for (int pt = 0; pt < 2; ++pt) { chh[pt] = (f32x4){0,0,0,0}; cx[pt] = (f32x4){0,0,0,0}; }
            #pragma unroll
            for (int kk = 0; kk < 4; ++kk) {
                const int boff = (ct * 16 + col) * D + SW(kk * 4 + quad, col) * 8;
                half8 Bhi = *(const half8*)&eh[boff];
                half8 Blo = *(const half8*)&el[boff];
                #pragma unroll
                for (int pt = 0; pt < 2; ++pt) {
                    chh[pt] = __builtin_amdgcn_mfma_f32_16x16x32_f16(ahi[pt][kk], Bhi, chh[pt], 0, 0, 0);
                    cx[pt]  = __builtin_amdgcn_mfma_f32_16x16x32_f16(ahi[pt][kk], Blo, cx[pt], 0, 0, 0);
                    cx[pt]  = __builtin_amdgcn_mfma_f32_16x16x32_f16(alo[pt][kk], Bhi, cx[pt], 0, 0, 0);
                }
            }
            const int lcode = ch * 32 + ct * 16 + col;
            const float esqT = esq_s[lcode];
            const int gcode = c0 + lcode;
            #pragma unroll
            for (int pt = 0; pt < 2; ++pt) {
                #pragma unroll
                for (int r = 0; r < 4; ++r) {
                    float s2 = fmaf(chh[pt][r], C1, fmaf(cx[pt][r], C2, -esqT));
                    lrun[pt][r] += exp2f(s2);
                    if (s2 > bv[pt][r]) { bv[pt][r] = s2; bi[pt][r] = gcode; }  // codes ascend
                }
            }
        }
        __syncthreads();   // drains next-chunk DMA; guards buffer reuse
    }

    #pragma unroll
    for (int pt = 0; pt < 2; ++pt) {
        #pragma unroll
        for (int r = 0; r < 4; ++r) {
            float v = bv[pt][r]; int idx = bi[pt][r]; float l = lrun[pt][r];
            #pragma unroll
            for (int off = 8; off >= 1; off >>= 1) {
                float ov = __shfl_xor(v, off, 16);
                int   oi = __shfl_xor(idx, off, 16);
                float ol = __shfl_xor(l, off, 16);
                l += ol;
                if (ov > v || (ov == v && oi < idx)) { v = ov; idx = oi; }
            }
            if (col == 0) {
                size_t o = (size_t)blockIdx.y * NPTS + p0w + pt * 16 + quad * 4 + r;
                pm[o] = v; pl[o] = l; pidx[o] = idx;
            }
        }
    }
}

// ---------------------------------------------------------------------------
// Combine: per point, reduce 4 code-slice partials -> r=1/sum(l), argmax.
// ---------------------------------------------------------------------------
__global__ void combine_kernel(const float* __restrict__ pm, const float* __restrict__ pl,
                               const int* __restrict__ pidx,
                               float* __restrict__ r_buf, int* __restrict__ idx_buf,
                               float* __restrict__ ind_out) {
    const int p = blockIdx.x * 256 + threadIdx.x;
    float bm = -INFINITY; int bi = 0; float l = 0.0f;
    #pragma unroll
    for (int sl = 0; sl < A_CSLICES; ++sl) {   // slices ascend in code
        size_t o = (size_t)sl * NPTS + p;
        float v = pm[o];
        l += pl[o];
        if (v > bm) { bm = v; bi = pidx[o]; }
    }
    r_buf[p] = 1.0f / l;
    idx_buf[p] = bi;
    ind_out[p] = (float)bi;
}

// ---------------------------------------------------------------------------
// Sweep B: point-resident, same skeleton as sweepA; rr in regs (loaded once);
// per ct: cross-quad sum + one LDS-atomic into bins; block flushes once.
// ---------------------------------------------------------------------------
__global__ __launch_bounds__(256, 4)
void sweepB_kernel(const _Float16* __restrict__ xhi_g, const _Float16* __restrict__ xlo_g,
                   const _Float16* __restrict__ ehi_g, const _Float16* __restrict__ elo_g,
                   const float* __restrict__ e_sqt_g, const float* __restrict__ r_buf,
                   float* __restrict__ classacc) {
    __shared__ _Float16 EHI[2][32 * D];
    __shared__ _Float16 ELO[2][32 * D];
    __shared__ float esq_s[A_CODES];
    __shared__ float bins[A_CODES];

    const int tid  = threadIdx.x;
    const int w    = tid >> 6;
    const int lane = tid & 63;
    const int col  = lane & 15;
    const int quad = lane >> 4;
    const int c0   = blockIdx.y * A_CODES;
    const int p0w  = blockIdx.x * 128 + w * 32;

    dma32(ehi_g, EHI[0], c0, w, lane);
    dma32(elo_g, ELO[0], c0, w, lane);
    for (int i = tid; i < A_CODES; i += 256) { esq_s[i] = e_sqt_g[c0 + i]; bins[i] = 0.0f; }

    half8 ahi[2][4], alo[2][4];
    load_a(xhi_g, xlo_g, p0w, col, quad, ahi, alo);

    float rr[2][4];
    #pragma unroll
    for (int pt = 0; pt < 2; ++pt)
        #pragma unroll
        for (int r = 0; r < 4; ++r)
            rr[pt][r] = r_buf[p0w + pt * 16 + quad * 4 + r];

    __syncthreads();

    for (int ch = 0; ch < A_NCH; ++ch) {
        const int cur = ch & 1;
        if (ch + 1 < A_NCH) {
            dma32(ehi_g, EHI[cur ^ 1], c0 + (ch + 1) * 32, w, lane);
            dma32(elo_g, ELO[cur ^ 1], c0 + (ch + 1) * 32, w, lane);
        }
        const _Float16* eh = EHI[cur];
        const _Float16* el = ELO[cur];

        #pragma unroll
        for (int ct = 0; ct < 2; ++ct) {
            f32x4 chh[2], cx[2];
            #pragma unroll
            for (int pt = 0; pt < 2; ++pt) { chh[pt] = (f32x4){0,0,0,0}; cx[pt] = (f32x4){0,0,0,0}; }
            #pragma unroll
            for (int kk = 0; kk < 4; ++kk) {
                const int boff = (ct * 16 + col) * D + SW(kk * 4 + quad, col) * 8;
                half8 Bhi = *(const half8*)&eh[boff];
                half8 Blo = *(const half8*)&el[boff];
                #pragma unroll
                for (int pt = 0; pt < 2; ++pt) {
                    chh[pt] = __builtin_amdgcn_mfma_f32_16x16x32_f16(ahi[pt][kk], Bhi, chh[pt], 0, 0, 0);
                    cx[pt]  = __builtin_amdgcn_mfma_f32_16x16x32_f16(ahi[pt][kk], Blo, cx[pt], 0, 0, 0);
                    cx[pt]  = __builtin_amdgcn_mfma_f32_16x16x32_f16(alo[pt][kk], Bhi, cx[pt], 0, 0, 0);
                }
            }
            const int lcode = ch * 32 + ct * 16 + col;
            const float esqT = esq_s[lcode];
            float wsum = 0.0f;
            #pragma unroll
            for (int pt = 0; pt < 2; ++pt) {
                #pragma unroll
                for (int r = 0; r < 4; ++r) {
                    float s2 = fmaf(chh[pt][r], C1, fmaf(cx[pt][r], C2, -esqT));
                    wsum += exp2f(s2) * rr[pt][r];
                }
            }
            wsum += __shfl_xor(wsum, 16, 64);   // sum the 4 quads (same code col)
            wsum += __shfl_xor(wsum, 32, 64);
            if (quad == 0) atomicAdd(&bins[lcode], wsum);
        }
        __syncthreads();
    }

    for (int i = tid; i < A_CODES; i += 256)
        atomicAdd(&classacc[c0 + i], bins[i]);
}

// ---------------------------------------------------------------------------
__global__ void gather_kernel(const float* __restrict__ embed,
                              const int* __restrict__ idx_buf,
                              float* __restrict__ q_out) {
    const int j = blockIdx.x * 256 + threadIdx.x;
    const int row = j >> 5;
    const int d4 = j & 31;
    reinterpret_cast<float4*>(q_out)[(size_t)row * 32 + d4] =
        reinterpret_cast<const float4*>(embed)[(size_t)idx_buf[row] * 32 + d4];
}

__global__ void finalize_kernel(const float* __restrict__ classacc,
                                float* __restrict__ loss_out, int N, int K) {
    __shared__ float red[256];
    const int tid = threadIdx.x;
    float s = 0.0f;
    const float invN = 1.0f / (float)N;
    for (int i = tid; i < K; i += 256) {
        float cp = classacc[i] * invN;
        s += cp * logf(cp + 1e-6f);
    }
    red[tid] = s;
    __syncthreads();
    for (int off = 128; off > 0; off >>= 1) {
        if (tid < off) red[tid] += red[tid + off];
        __syncthreads();
    }
    if (tid == 0) loss_out[0] = red[0];
}

extern "C" void kernel_launch(void* const* d_in, const int* in_sizes, int n_in,
                              void* d_out, int out_size, void* d_ws, size_t ws_size,
                              hipStream_t stream) {
    const float* x     = (const float*)d_in[0];
    const float* embed = (const float*)d_in[1];

    float* out      = (float*)d_out;
    float* q_out    = out;
    float* ind_out  = out + (size_t)NPTS * D;
    float* loss_out = ind_out + NPTS;

    float*    e_sqt = (float*)d_ws;                          // 2048 f
    float*    cacc  = e_sqt + KCODES;                        // 2048 f
    _Float16* ehi   = (_Float16*)(cacc + KCODES);            // K*D halves (swizzled)
    _Float16* elo   = ehi + (size_t)KCODES * D;
    _Float16* xhi   = elo + (size_t)KCODES * D;              // N*D halves (swizzled)
    _Float16* xlo   = xhi + (size_t)NPTS * D;
    float*    pm    = (float*)(xlo + (size_t)NPTS * D);      // 4*N
    float*    pl    = pm + (size_t)A_CSLICES * NPTS;         // 4*N
    int*      pidx  = (int*)(pl + (size_t)A_CSLICES * NPTS); // 4*N
    float*    r_buf = (float*)(pidx + (size_t)A_CSLICES * NPTS); // N
    int*      idx_buf = (int*)(r_buf + NPTS);                // N

    prep_kernel<<<KCODES / 64 + NPTS / 64, 256, 0, stream>>>(
        embed, x, e_sqt, ehi, elo, xhi, xlo, cacc);
    sweepA_kernel<<<dim3(NPTS / 128, A_CSLICES), 256, 0, stream>>>(
        xhi, xlo, ehi, elo, e_sqt, pm, pl, pidx);
    combine_kernel<<<NPTS / 256, 256, 0, stream>>>(pm, pl, pidx, r_buf, idx_buf, ind_out);
    sweepB_kernel<<<dim3(NPTS / 128, A_CSLICES), 256, 0, stream>>>(
        xhi, xlo, ehi, elo, e_sqt, r_buf, cacc);
    gather_kernel<<<NPTS * 32 / 256, 256, 0, stream>>>(embed, idx_buf, q_out);
    finalize_kernel<<<1, 256, 0, stream>>>(cacc, loss_out, NPTS, KCODES);
}

// Round 8
// 207.464 us; speedup vs baseline: 1.1065x; 1.1065x over previous
//
#include <hip/hip_runtime.h>
#include <math.h>

#define D        128
#define KCODES   2048
#define NPTS     32768
#define LO_SCALE 4096.0f
// exp2-domain: s2 = (2*dot - e^2) * log2e / T
#define C1       3.205988979753252f          // 2*log2e/T
#define C2       (C1 / LO_SCALE)
#define ESQ_SCALE 1.602994489876626f         // log2e/T

#define A_CSLICES 4
#define A_CODES   512                        // codes per slice
#define A_NCH     (A_CODES / 32)             // 16 chunks of 32 codes

// swizzle: logical 16B-group G of row r stored at slot (G ^ r) & 15
#define SW(G, r)  (((G) ^ (r)) & 15)

typedef _Float16 half8 __attribute__((ext_vector_type(8)));
typedef float    f32x4 __attribute__((ext_vector_type(4)));

// ---------------------------------------------------------------------------
// Prep (fused): fp16 hi/lo split of embed AND x (lo pre-scaled by 4096) into
// XOR-swizzled rows; e_sqt; zero classacc. 4 threads per row.
// ---------------------------------------------------------------------------
__device__ __forceinline__ void split_row_part(const float* __restrict__ src,
                                               _Float16* __restrict__ hi_row,
                                               _Float16* __restrict__ lo_row,
                                               int part, int rkey, float* ss) {
    #pragma unroll
    for (int g = 0; g < 4; ++g) {
        const int G = part * 4 + g;
        half8 h, l;
        float s = 0.0f;
        #pragma unroll
        for (int j = 0; j < 8; ++j) {
            float v = src[g * 8 + j];
            _Float16 hh = (_Float16)v;
            h[j] = hh;
            l[j] = (_Float16)((v - (float)hh) * LO_SCALE);
            s += v * v;
        }
        *ss += s;
        const int slot = SW(G, rkey);
        *(half8*)(hi_row + slot * 8) = h;
        *(half8*)(lo_row + slot * 8) = l;
    }
}

__global__ void prep_kernel(const float* __restrict__ embed, const float* __restrict__ x,
                            float* __restrict__ e_sqt,
                            _Float16* __restrict__ ehi, _Float16* __restrict__ elo,
                            _Float16* __restrict__ xhi, _Float16* __restrict__ xlo,
                            float* __restrict__ cacc) {
    const int b = blockIdx.x;
    const int tid = threadIdx.x;
    const int part = tid & 3;
    float ss = 0.0f;
    if (b < KCODES / 64) {
        const int row = b * 64 + (tid >> 2);
        split_row_part(embed + (size_t)row * D + part * 32,
                       ehi + (size_t)row * D, elo + (size_t)row * D, part, row & 15, &ss);
        ss += __shfl_xor(ss, 1, 64);
        ss += __shfl_xor(ss, 2, 64);
        if (part == 0) e_sqt[row] = ss * ESQ_SCALE;
        if (part == 1) cacc[row] = 0.0f;
    } else {
        const int row = (b - KCODES / 64) * 64 + (tid >> 2);
        split_row_part(x + (size_t)row * D + part * 32,
                       xhi + (size_t)row * D, xlo + (size_t)row * D, part, row & 15, &ss);
    }
}

// async DMA of one 32-row chunk (8 rows/wave, 256 B/row) into LDS
__device__ __forceinline__ void dma32(const _Float16* __restrict__ g_base,
                                      _Float16* lds_base, int row0, int w, int lane) {
    const char* src = (const char*)g_base + (size_t)(row0 + 8 * w) * 256 + lane * 16;
    char* dst = (char*)lds_base + 8 * w * 256;
    #pragma unroll
    for (int i = 0; i < 2; ++i) {
        __builtin_amdgcn_global_load_lds(
            (const __attribute__((address_space(1))) unsigned int*)(src + i * 1024),
            (__attribute__((address_space(3))) unsigned int*)(dst + i * 1024),
            16, 0, 0);
    }
}

// load this lane's resident A fragments (32 points, swizzled hi/lo)
__device__ __forceinline__ void load_a(const _Float16* __restrict__ xhi_g,
                                       const _Float16* __restrict__ xlo_g,
                                       int p0w, int col, int quad,
                                       half8 ahi[2][4], half8 alo[2][4]) {
    #pragma unroll
    for (int pt = 0; pt < 2; ++pt) {
        const int pr = p0w + pt * 16 + col;          // pr & 15 == col
        #pragma unroll
        for (int kk = 0; kk < 4; ++kk) {
            const int slot = SW(kk * 4 + quad, col);
            ahi[pt][kk] = *(const half8*)(xhi_g + (size_t)pr * D + slot * 8);
            alo[pt][kk] = *(const half8*)(xlo_g + (size_t)pr * D + slot * 8);
        }
    }
}

// ---------------------------------------------------------------------------
// Sweep A: point-resident (32 pts/wave), codes stream via dbuf LDS DMA.
// Softmax/argmax state in registers, flushed once. Partials [4][NPTS].
// NOTE: __launch_bounds__(256, 2) — min-waves=4 forced the allocator to a
// 64-VGPR budget and spilled the resident state (R7: WRITE_SIZE 37 MB).
// With cap 256 the body lands ~120 VGPR -> 4 waves/SIMD from actual usage.
// ---------------------------------------------------------------------------
__global__ __launch_bounds__(256, 2)
void sweepA_kernel(const _Float16* __restrict__ xhi_g, const _Float16* __restrict__ xlo_g,
                   const _Float16* __restrict__ ehi_g, const _Float16* __restrict__ elo_g,
                   const float* __restrict__ e_sqt_g,
                   float* __restrict__ pm, float* __restrict__ pl, int* __restrict__ pidx) {
    __shared__ _Float16 EHI[2][32 * D];   // 2 x 8 KB
    __shared__ _Float16 ELO[2][32 * D];   // 2 x 8 KB
    __shared__ float esq_s[A_CODES];      // 2 KB

    const int tid  = threadIdx.x;
    const int w    = tid >> 6;
    const int lane = tid & 63;
    const int col  = lane & 15;
    const int quad = lane >> 4;
    const int c0   = blockIdx.y * A_CODES;
    const int p0w  = blockIdx.x * 128 + w * 32;

    dma32(ehi_g, EHI[0], c0, w, lane);
    dma32(elo_g, ELO[0], c0, w, lane);
    for (int i = tid; i < A_CODES; i += 256) esq_s[i] = e_sqt_g[c0 + i];

    half8 ahi[2][4], alo[2][4];
    load_a(xhi_g, xlo_g, p0w, col, quad, ahi, alo);

    float lrun[2][4], bv[2][4];
    int   bi[2][4];
    #pragma unroll
    for (int pt = 0; pt < 2; ++pt)
        #pragma unroll
        for (int r = 0; r < 4; ++r) { lrun[pt][r] = 0.f; bv[pt][r] = -INFINITY; bi[pt][r] = 0; }

    __syncthreads();   // chunk0 DMA + esq ready

    for (int ch = 0; ch < A_NCH; ++ch) {
        const int cur = ch & 1;
        if (ch + 1 < A_NCH) {
            dma32(ehi_g, EHI[cur ^ 1], c0 + (ch + 1) * 32, w, lane);
            dma32(elo_g, ELO[cur ^ 1], c0 + (ch + 1) * 32, w, lane);
        }
        const _Float16* eh = EHI[cur];
        const _Float16* el = ELO[cur];

        #pragma unroll
        for (int ct = 0; ct < 2; ++ct) {
            f32x4 chh[2], cx[2];
            #pragma unroll
            for (int pt = 0; pt < 2; ++pt) { chh[pt] = (f32x4){0,0,0,0}; cx[pt] = (f32x4){0,0,0,0}; }
            #pragma unroll
            for (int kk = 0; kk < 4; ++kk) {
                const int boff = (ct * 16 + col) * D + SW(kk * 4 + quad, col) * 8;
                half8 Bhi = *(const half8*)&eh[boff];
                half8 Blo = *(const half8*)&el[boff];
                #pragma unroll
                for (int pt = 0; pt < 2; ++pt) {
                    chh[pt] = __builtin_amdgcn_mfma_f32_16x16x32_f16(ahi[pt][kk], Bhi, chh[pt], 0, 0, 0);
                    cx[pt]  = __builtin_amdgcn_mfma_f32_16x16x32_f16(ahi[pt][kk], Blo, cx[pt], 0, 0, 0);
                    cx[pt]  = __builtin_amdgcn_mfma_f32_16x16x32_f16(alo[pt][kk], Bhi, cx[pt], 0, 0, 0);
                }
            }
            const int lcode = ch * 32 + ct * 16 + col;
            const float esqT = esq_s[lcode];
            const int gcode = c0 + lcode;
            #pragma unroll
            for (int pt = 0; pt < 2; ++pt) {
                #pragma unroll
                for (int r = 0; r < 4; ++r) {
                    float s2 = fmaf(chh[pt][r], C1, fmaf(cx[pt][r], C2, -esqT));
                    lrun[pt][r] += exp2f(s2);
                    if (s2 > bv[pt][r]) { bv[pt][r] = s2; bi[pt][r] = gcode; }  // codes ascend
                }
            }
        }
        __syncthreads();   // drains next-chunk DMA; guards buffer reuse
    }

    #pragma unroll
    for (int pt = 0; pt < 2; ++pt) {
        #pragma unroll
        for (int r = 0; r < 4; ++r) {
            float v = bv[pt][r]; int idx = bi[pt][r]; float l = lrun[pt][r];
            #pragma unroll
            for (int off = 8; off >= 1; off >>= 1) {
                float ov = __shfl_xor(v, off, 16);
                int   oi = __shfl_xor(idx, off, 16);
                float ol = __shfl_xor(l, off, 16);
                l += ol;
                if (ov > v || (ov == v && oi < idx)) { v = ov; idx = oi; }
            }
            if (col == 0) {
                size_t o = (size_t)blockIdx.y * NPTS + p0w + pt * 16 + quad * 4 + r;
                pm[o] = v; pl[o] = l; pidx[o] = idx;
            }
        }
    }
}

// ---------------------------------------------------------------------------
// Combine: per point, reduce 4 code-slice partials -> r=1/sum(l), argmax.
// ---------------------------------------------------------------------------
__global__ void combine_kernel(const float* __restrict__ pm, const float* __restrict__ pl,
                               const int* __restrict__ pidx,
                               float* __restrict__ r_buf, int* __restrict__ idx_buf,
                               float* __restrict__ ind_out) {
    const int p = blockIdx.x * 256 + threadIdx.x;
    float bm = -INFINITY; int bi = 0; float l = 0.0f;
    #pragma unroll
    for (int sl = 0; sl < A_CSLICES; ++sl) {   // slices ascend in code
        size_t o = (size_t)sl * NPTS + p;
        float v = pm[o];
        l += pl[o];
        if (v > bm) { bm = v; bi = pidx[o]; }
    }
    r_buf[p] = 1.0f / l;
    idx_buf[p] = bi;
    ind_out[p] = (float)bi;
}

// ---------------------------------------------------------------------------
// Sweep B: point-resident, same skeleton as sweepA; rr in regs (loaded once);
// per ct: cross-quad sum + one LDS-atomic into bins; block flushes once.
// ---------------------------------------------------------------------------
__global__ __launch_bounds__(256, 2)
void sweepB_kernel(const _Float16* __restrict__ xhi_g, const _Float16* __restrict__ xlo_g,
                   const _Float16* __restrict__ ehi_g, const _Float16* __restrict__ elo_g,
                   const float* __restrict__ e_sqt_g, const float* __restrict__ r_buf,
                   float* __restrict__ classacc) {
    __shared__ _Float16 EHI[2][32 * D];
    __shared__ _Float16 ELO[2][32 * D];
    __shared__ float esq_s[A_CODES];
    __shared__ float bins[A_CODES];

    const int tid  = threadIdx.x;
    const int w    = tid >> 6;
    const int lane = tid & 63;
    const int col  = lane & 15;
    const int quad = lane >> 4;
    const int c0   = blockIdx.y * A_CODES;
    const int p0w  = blockIdx.x * 128 + w * 32;

    dma32(ehi_g, EHI[0], c0, w, lane);
    dma32(elo_g, ELO[0], c0, w, lane);
    for (int i = tid; i < A_CODES; i += 256) { esq_s[i] = e_sqt_g[c0 + i]; bins[i] = 0.0f; }

    half8 ahi[2][4], alo[2][4];
    load_a(xhi_g, xlo_g, p0w, col, quad, ahi, alo);

    float rr[2][4];
    #pragma unroll
    for (int pt = 0; pt < 2; ++pt)
        #pragma unroll
        for (int r = 0; r < 4; ++r)
            rr[pt][r] = r_buf[p0w + pt * 16 + quad * 4 + r];

    __syncthreads();

    for (int ch = 0; ch < A_NCH; ++ch) {
        const int cur = ch & 1;
        if (ch + 1 < A_NCH) {
            dma32(ehi_g, EHI[cur ^ 1], c0 + (ch + 1) * 32, w, lane);
            dma32(elo_g, ELO[cur ^ 1], c0 + (ch + 1) * 32, w, lane);
        }
        const _Float16* eh = EHI[cur];
        const _Float16* el = ELO[cur];

        #pragma unroll
        for (int ct = 0; ct < 2; ++ct) {
            f32x4 chh[2], cx[2];
            #pragma unroll
            for (int pt = 0; pt < 2; ++pt) { chh[pt] = (f32x4){0,0,0,0}; cx[pt] = (f32x4){0,0,0,0}; }
            #pragma unroll
            for (int kk = 0; kk < 4; ++kk) {
                const int boff = (ct * 16 + col) * D + SW(kk * 4 + quad, col) * 8;
                half8 Bhi = *(const half8*)&eh[boff];
                half8 Blo = *(const half8*)&el[boff];
                #pragma unroll
                for (int pt = 0; pt < 2; ++pt) {
                    chh[pt] = __builtin_amdgcn_mfma_f32_16x16x32_f16(ahi[pt][kk], Bhi, chh[pt], 0, 0, 0);
                    cx[pt]  = __builtin_amdgcn_mfma_f32_16x16x32_f16(ahi[pt][kk], Blo, cx[pt], 0, 0, 0);
                    cx[pt]  = __builtin_amdgcn_mfma_f32_16x16x32_f16(alo[pt][kk], Bhi, cx[pt], 0, 0, 0);
                }
            }
            const int lcode = ch * 32 + ct * 16 + col;
            const float esqT = esq_s[lcode];
            float wsum = 0.0f;
            #pragma unroll
            for (int pt = 0; pt < 2; ++pt) {
                #pragma unroll
                for (int r = 0; r < 4; ++r) {
                    float s2 = fmaf(chh[pt][r], C1, fmaf(cx[pt][r], C2, -esqT));
                    wsum += exp2f(s2) * rr[pt][r];
                }
            }
            wsum += __shfl_xor(wsum, 16, 64);   // sum the 4 quads (same code col)
            wsum += __shfl_xor(wsum, 32, 64);
            if (quad == 0) atomicAdd(&bins[lcode], wsum);
        }
        __syncthreads();
    }

    for (int i = tid; i < A_CODES; i += 256)
        atomicAdd(&classacc[c0 + i], bins[i]);
}

// ---------------------------------------------------------------------------
__global__ void gather_kernel(const float* __restrict__ embed,
                              const int* __restrict__ idx_buf,
                              float* __restrict__ q_out) {
    const int j = blockIdx.x * 256 + threadIdx.x;
    const int row = j >> 5;
    const int d4 = j & 31;
    reinterpret_cast<float4*>(q_out)[(size_t)row * 32 + d4] =
        reinterpret_cast<const float4*>(embed)[(size_t)idx_buf[row] * 32 + d4];
}

__global__ void finalize_kernel(const float* __restrict__ classacc,
                                float* __restrict__ loss_out, int N, int K) {
    __shared__ float red[256];
    const int tid = threadIdx.x;
    float s = 0.0f;
    const float invN = 1.0f / (float)N;
    for (int i = tid; i < K; i += 256) {
        float cp = classacc[i] * invN;
        s += cp * logf(cp + 1e-6f);
    }
    red[tid] = s;
    __syncthreads();
    for (int off = 128; off > 0; off >>= 1) {
        if (tid < off) red[tid] += red[tid + off];
        __syncthreads();
    }
    if (tid == 0) loss_out[0] = red[0];
}

extern "C" void kernel_launch(void* const* d_in, const int* in_sizes, int n_in,
                              void* d_out, int out_size, void* d_ws, size_t ws_size,
                              hipStream_t stream) {
    const float* x     = (const float*)d_in[0];
    const float* embed = (const float*)d_in[1];

    float* out      = (float*)d_out;
    float* q_out    = out;
    float* ind_out  = out + (size_t)NPTS * D;
    float* loss_out = ind_out + NPTS;

    float*    e_sqt = (float*)d_ws;                          // 2048 f
    float*    cacc  = e_sqt + KCODES;                        // 2048 f
    _Float16* ehi   = (_Float16*)(cacc + KCODES);            // K*D halves (swizzled)
    _Float16* elo   = ehi + (size_t)KCODES * D;
    _Float16* xhi   = elo + (size_t)KCODES * D;              // N*D halves (swizzled)
    _Float16* xlo   = xhi + (size_t)NPTS * D;
    float*    pm    = (float*)(xlo + (size_t)NPTS * D);      // 4*N
    float*    pl    = pm + (size_t)A_CSLICES * NPTS;         // 4*N
    int*      pidx  = (int*)(pl + (size_t)A_CSLICES * NPTS); // 4*N
    float*    r_buf = (float*)(pidx + (size_t)A_CSLICES * NPTS); // N
    int*      idx_buf = (int*)(r_buf + NPTS);                // N

    prep_kernel<<<KCODES / 64 + NPTS / 64, 256, 0, stream>>>(
        embed, x, e_sqt, ehi, elo, xhi, xlo, cacc);
    sweepA_kernel<<<dim3(NPTS / 128, A_CSLICES), 256, 0, stream>>>(
        xhi, xlo, ehi, elo, e_sqt, pm, pl, pidx);
    combine_kernel<<<NPTS / 256, 256, 0, stream>>>(pm, pl, pidx, r_buf, idx_buf, ind_out);
    sweepB_kernel<<<dim3(NPTS / 128, A_CSLICES), 256, 0, stream>>>(
        xhi, xlo, ehi, elo, e_sqt, r_buf, cacc);
    gather_kernel<<<NPTS * 32 / 256, 256, 0, stream>>>(embed, idx_buf, q_out);
    finalize_kernel<<<1, 256, 0, stream>>>(cacc, loss_out, NPTS, KCODES);
}

// Round 9
// 203.786 us; speedup vs baseline: 1.1265x; 1.0181x over previous
//
#include <hip/hip_runtime.h>
#include <math.h>

#define D        128
#define KCODES   2048
#define NPTS     32768
#define LO_SCALE 4096.0f
// exp2-domain: s2 = (2*dot - e^2) * log2e / T
#define C1       3.205988979753252f          // 2*log2e/T
#define C2       (C1 / LO_SCALE)
#define ESQ_SCALE 1.602994489876626f         // log2e/T

#define A_CSLICES 2
#define A_CODES   1024                       // codes per slice
#define CHUNK     64                         // codes staged per chunk
#define A_NCH     (A_CODES / CHUNK)          // 16 chunks

// swizzle: logical 16B-group G of row r stored at slot (G ^ r) & 15
#define SW(G, r)  (((G) ^ (r)) & 15)

typedef _Float16 half8 __attribute__((ext_vector_type(8)));
typedef float    f32x4 __attribute__((ext_vector_type(4)));

// ---------------------------------------------------------------------------
// Prep (fused): fp16 hi/lo split of embed AND x (lo pre-scaled by 4096) into
// XOR-swizzled rows; e_sqt; zero classacc. 4 threads per row.
// ---------------------------------------------------------------------------
__device__ __forceinline__ void split_row_part(const float* __restrict__ src,
                                               _Float16* __restrict__ hi_row,
                                               _Float16* __restrict__ lo_row,
                                               int part, int rkey, float* ss) {
    #pragma unroll
    for (int g = 0; g < 4; ++g) {
        const int G = part * 4 + g;
        half8 h, l;
        float s = 0.0f;
        #pragma unroll
        for (int j = 0; j < 8; ++j) {
            float v = src[g * 8 + j];
            _Float16 hh = (_Float16)v;
            h[j] = hh;
            l[j] = (_Float16)((v - (float)hh) * LO_SCALE);
            s += v * v;
        }
        *ss += s;
        const int slot = SW(G, rkey);
        *(half8*)(hi_row + slot * 8) = h;
        *(half8*)(lo_row + slot * 8) = l;
    }
}

__global__ void prep_kernel(const float* __restrict__ embed, const float* __restrict__ x,
                            float* __restrict__ e_sqt,
                            _Float16* __restrict__ ehi, _Float16* __restrict__ elo,
                            _Float16* __restrict__ xhi, _Float16* __restrict__ xlo,
                            float* __restrict__ cacc) {
    const int b = blockIdx.x;
    const int tid = threadIdx.x;
    const int part = tid & 3;
    float ss = 0.0f;
    if (b < KCODES / 64) {
        const int row = b * 64 + (tid >> 2);
        split_row_part(embed + (size_t)row * D + part * 32,
                       ehi + (size_t)row * D, elo + (size_t)row * D, part, row & 15, &ss);
        ss += __shfl_xor(ss, 1, 64);
        ss += __shfl_xor(ss, 2, 64);
        if (part == 0) e_sqt[row] = ss * ESQ_SCALE;
        if (part == 1) cacc[row] = 0.0f;
    } else {
        const int row = (b - KCODES / 64) * 64 + (tid >> 2);
        split_row_part(x + (size_t)row * D + part * 32,
                       xhi + (size_t)row * D, xlo + (size_t)row * D, part, row & 15, &ss);
    }
}

// async DMA of one 64-row chunk (16 rows/wave, 256 B/row) into LDS
__device__ __forceinline__ void dma64(const _Float16* __restrict__ g_base,
                                      _Float16* lds_base, int row0, int w, int lane) {
    const char* src = (const char*)g_base + (size_t)(row0 + 16 * w) * 256 + lane * 16;
    char* dst = (char*)lds_base + 16 * w * 256;
    #pragma unroll
    for (int i = 0; i < 4; ++i) {
        __builtin_amdgcn_global_load_lds(
            (const __attribute__((address_space(1))) unsigned int*)(src + i * 1024),
            (__attribute__((address_space(3))) unsigned int*)(dst + i * 1024),
            16, 0, 0);
    }
}

// load this lane's resident A fragments (32 points, swizzled hi/lo)
__device__ __forceinline__ void load_a(const _Float16* __restrict__ xhi_g,
                                       const _Float16* __restrict__ xlo_g,
                                       int p0w, int col, int quad,
                                       half8 ahi[2][4], half8 alo[2][4]) {
    #pragma unroll
    for (int pt = 0; pt < 2; ++pt) {
        const int pr = p0w + pt * 16 + col;          // pr & 15 == col
        #pragma unroll
        for (int kk = 0; kk < 4; ++kk) {
            const int slot = SW(kk * 4 + quad, col);
            ahi[pt][kk] = *(const half8*)(xhi_g + (size_t)pr * D + slot * 8);
            alo[pt][kk] = *(const half8*)(xlo_g + (size_t)pr * D + slot * 8);
        }
    }
}

// ---------------------------------------------------------------------------
// Sweep A: point-resident (32 pts/wave), 64-code chunks stream via dbuf DMA.
// Softmax/argmax state in registers, flushed once. Partials [2][NPTS].
// ---------------------------------------------------------------------------
__global__ __launch_bounds__(256, 2)
void sweepA_kernel(const _Float16* __restrict__ xhi_g, const _Float16* __restrict__ xlo_g,
                   const _Float16* __restrict__ ehi_g, const _Float16* __restrict__ elo_g,
                   const float* __restrict__ e_sqt_g,
                   float* __restrict__ pm, float* __restrict__ pl, int* __restrict__ pidx) {
    __shared__ _Float16 EHI[2][CHUNK * D];   // 2 x 16 KB
    __shared__ _Float16 ELO[2][CHUNK * D];   // 2 x 16 KB
    __shared__ float esq_s[A_CODES];         // 4 KB

    const int tid  = threadIdx.x;
    const int w    = tid >> 6;
    const int lane = tid & 63;
    const int col  = lane & 15;
    const int quad = lane >> 4;
    const int c0   = blockIdx.y * A_CODES;
    const int p0w  = blockIdx.x * 128 + w * 32;

    dma64(ehi_g, EHI[0], c0, w, lane);
    dma64(elo_g, ELO[0], c0, w, lane);
    for (int i = tid; i < A_CODES; i += 256) esq_s[i] = e_sqt_g[c0 + i];

    half8 ahi[2][4], alo[2][4];
    load_a(xhi_g, xlo_g, p0w, col, quad, ahi, alo);

    float lrun[2][4], bv[2][4];
    int   bi[2][4];
    #pragma unroll
    for (int pt = 0; pt < 2; ++pt)
        #pragma unroll
        for (int r = 0; r < 4; ++r) { lrun[pt][r] = 0.f; bv[pt][r] = -INFINITY; bi[pt][r] = 0; }

    __syncthreads();   // chunk0 DMA + esq ready

    for (int ch = 0; ch < A_NCH; ++ch) {
        const int cur = ch & 1;
        if (ch + 1 < A_NCH) {
            dma64(ehi_g, EHI[cur ^ 1], c0 + (ch + 1) * CHUNK, w, lane);
            dma64(elo_g, ELO[cur ^ 1], c0 + (ch + 1) * CHUNK, w, lane);
        }
        const _Float16* eh = EHI[cur];
        const _Float16* el = ELO[cur];

        #pragma unroll
        for (int ct = 0; ct < 4; ++ct) {
            f32x4 chh[2], cx[2];
            #pragma unroll
            for (int pt = 0; pt < 2; ++pt) { chh[pt] = (f32x4){0,0,0,0}; cx[pt] = (f32x4){0,0,0,0}; }
            #pragma unroll
            for (int kk = 0; kk < 4; ++kk) {
                const int boff = (ct * 16 + col) * D + SW(kk * 4 + quad, col) * 8;
                half8 Bhi = *(const half8*)&eh[boff];
                half8 Blo = *(const half8*)&el[boff];
                #pragma unroll
                for (int pt = 0; pt < 2; ++pt) {
                    chh[pt] = __builtin_amdgcn_mfma_f32_16x16x32_f16(ahi[pt][kk], Bhi, chh[pt], 0, 0, 0);
                    cx[pt]  = __builtin_amdgcn_mfma_f32_16x16x32_f16(ahi[pt][kk], Blo, cx[pt], 0, 0, 0);
                    cx[pt]  = __builtin_amdgcn_mfma_f32_16x16x32_f16(alo[pt][kk], Bhi, cx[pt], 0, 0, 0);
                }
            }
            const int lcode = ch * CHUNK + ct * 16 + col;
            const float esqT = esq_s[lcode];
            const int gcode = c0 + lcode;
            #pragma unroll
            for (int pt = 0; pt < 2; ++pt) {
                #pragma unroll
                for (int r = 0; r < 4; ++r) {
                    float s2 = fmaf(chh[pt][r], C1, fmaf(cx[pt][r], C2, -esqT));
                    lrun[pt][r] += exp2f(s2);
                    if (s2 > bv[pt][r]) { bv[pt][r] = s2; bi[pt][r] = gcode; }  // codes ascend
                }
            }
        }
        __syncthreads();   // drains next-chunk DMA; guards buffer reuse
    }

    #pragma unroll
    for (int pt = 0; pt < 2; ++pt) {
        #pragma unroll
        for (int r = 0; r < 4; ++r) {
            float v = bv[pt][r]; int idx = bi[pt][r]; float l = lrun[pt][r];
            #pragma unroll
            for (int off = 8; off >= 1; off >>= 1) {
                float ov = __shfl_xor(v, off, 16);
                int   oi = __shfl_xor(idx, off, 16);
                float ol = __shfl_xor(l, off, 16);
                l += ol;
                if (ov > v || (ov == v && oi < idx)) { v = ov; idx = oi; }
            }
            if (col == 0) {
                size_t o = (size_t)blockIdx.y * NPTS + p0w + pt * 16 + quad * 4 + r;
                pm[o] = v; pl[o] = l; pidx[o] = idx;
            }
        }
    }
}

// ---------------------------------------------------------------------------
// Sweep B (fused combine+gather): each block re-derives r/idx for its 128
// points from the partials; streams codes, accumulates bins; y==0 blocks
// write ind_out and gather quantize rows at the end.
// ---------------------------------------------------------------------------
__global__ __launch_bounds__(256, 2)
void sweepB_kernel(const _Float16* __restrict__ xhi_g, const _Float16* __restrict__ xlo_g,
                   const _Float16* __restrict__ ehi_g, const _Float16* __restrict__ elo_g,
                   const float* __restrict__ e_sqt_g,
                   const float* __restrict__ pm, const float* __restrict__ pl,
                   const int* __restrict__ pidx,
                   float* __restrict__ classacc, const float* __restrict__ embed,
                   float* __restrict__ q_out, float* __restrict__ ind_out) {
    __shared__ _Float16 EHI[2][CHUNK * D];
    __shared__ _Float16 ELO[2][CHUNK * D];
    __shared__ float esq_s[A_CODES];
    __shared__ float bins[A_CODES];
    __shared__ float r_s[128];
    __shared__ int   idx_s[128];

    const int tid  = threadIdx.x;
    const int w    = tid >> 6;
    const int lane = tid & 63;
    const int col  = lane & 15;
    const int quad = lane >> 4;
    const int c0   = blockIdx.y * A_CODES;
    const int p0   = blockIdx.x * 128;
    const int p0w  = p0 + w * 32;

    dma64(ehi_g, EHI[0], c0, w, lane);
    dma64(elo_g, ELO[0], c0, w, lane);
    for (int i = tid; i < A_CODES; i += 256) { esq_s[i] = e_sqt_g[c0 + i]; bins[i] = 0.0f; }

    // inline combine for this block's 128 points
    if (tid < 128) {
        const int p = p0 + tid;
        float bm = -INFINITY; int bidx = 0; float l = 0.0f;
        #pragma unroll
        for (int sl = 0; sl < A_CSLICES; ++sl) {   // slices ascend in code
            size_t o = (size_t)sl * NPTS + p;
            float v = pm[o];
            l += pl[o];
            if (v > bm) { bm = v; bidx = pidx[o]; }
        }
        r_s[tid] = 1.0f / l;
        idx_s[tid] = bidx;
        if (blockIdx.y == 0) ind_out[p] = (float)bidx;
    }

    half8 ahi[2][4], alo[2][4];
    load_a(xhi_g, xlo_g, p0w, col, quad, ahi, alo);

    __syncthreads();   // chunk0 DMA + combine ready

    float rr[2][4];
    #pragma unroll
    for (int pt = 0; pt < 2; ++pt)
        #pragma unroll
        for (int r = 0; r < 4; ++r)
            rr[pt][r] = r_s[w * 32 + pt * 16 + quad * 4 + r];

    for (int ch = 0; ch < A_NCH; ++ch) {
        const int cur = ch & 1;
        if (ch + 1 < A_NCH) {
            dma64(ehi_g, EHI[cur ^ 1], c0 + (ch + 1) * CHUNK, w, lane);
            dma64(elo_g, ELO[cur ^ 1], c0 + (ch + 1) * CHUNK, w, lane);
        }
        const _Float16* eh = EHI[cur];
        const _Float16* el = ELO[cur];

        #pragma unroll
        for (int ct = 0; ct < 4; ++ct) {
            f32x4 chh[2], cx[2];
            #pragma unroll
            for (int pt = 0; pt < 2; ++pt) { chh[pt] = (f32x4){0,0,0,0}; cx[pt] = (f32x4){0,0,0,0}; }
            #pragma unroll
            for (int kk = 0; kk < 4; ++kk) {
                const int boff = (ct * 16 + col) * D + SW(kk * 4 + quad, col) * 8;
                half8 Bhi = *(const half8*)&eh[boff];
                half8 Blo = *(const half8*)&el[boff];
                #pragma unroll
                for (int pt = 0; pt < 2; ++pt) {
                    chh[pt] = __builtin_amdgcn_mfma_f32_16x16x32_f16(ahi[pt][kk], Bhi, chh[pt], 0, 0, 0);
                    cx[pt]  = __builtin_amdgcn_mfma_f32_16x16x32_f16(ahi[pt][kk], Blo, cx[pt], 0, 0, 0);
                    cx[pt]  = __builtin_amdgcn_mfma_f32_16x16x32_f16(alo[pt][kk], Bhi, cx[pt], 0, 0, 0);
                }
            }
            const int lcode = ch * CHUNK + ct * 16 + col;
            const float esqT = esq_s[lcode];
            float wsum = 0.0f;
            #pragma unroll
            for (int pt = 0; pt < 2; ++pt) {
                #pragma unroll
                for (int r = 0; r < 4; ++r) {
                    float s2 = fmaf(chh[pt][r], C1, fmaf(cx[pt][r], C2, -esqT));
                    wsum += exp2f(s2) * rr[pt][r];
                }
            }
            wsum += __shfl_xor(wsum, 16, 64);   // sum the 4 quads (same code col)
            wsum += __shfl_xor(wsum, 32, 64);
            if (quad == 0) atomicAdd(&bins[lcode], wsum);
        }
        __syncthreads();
    }

    for (int i = tid; i < A_CODES; i += 256)
        atomicAdd(&classacc[c0 + i], bins[i]);

    // quantize gather for this block's 128 points (y==0 only)
    if (blockIdx.y == 0) {
        const float4* emb4 = (const float4*)embed;
        float4* q4 = (float4*)q_out;
        #pragma unroll
        for (int it = 0; it < 16; ++it) {
            int j = tid + it * 256;          // 4096 float4 = 128 rows x 32
            int row = j >> 5, d4 = j & 31;
            q4[(size_t)(p0 + row) * 32 + d4] = emb4[(size_t)idx_s[row] * 32 + d4];
        }
    }
}

// ---------------------------------------------------------------------------
__global__ void finalize_kernel(const float* __restrict__ classacc,
                                float* __restrict__ loss_out, int N, int K) {
    __shared__ float red[256];
    const int tid = threadIdx.x;
    float s = 0.0f;
    const float invN = 1.0f / (float)N;
    for (int i = tid; i < K; i += 256) {
        float cp = classacc[i] * invN;
        s += cp * logf(cp + 1e-6f);
    }
    red[tid] = s;
    __syncthreads();
    for (int off = 128; off > 0; off >>= 1) {
        if (tid < off) red[tid] += red[tid + off];
        __syncthreads();
    }
    if (tid == 0) loss_out[0] = red[0];
}

extern "C" void kernel_launch(void* const* d_in, const int* in_sizes, int n_in,
                              void* d_out, int out_size, void* d_ws, size_t ws_size,
                              hipStream_t stream) {
    const float* x     = (const float*)d_in[0];
    const float* embed = (const float*)d_in[1];

    float* out      = (float*)d_out;
    float* q_out    = out;
    float* ind_out  = out + (size_t)NPTS * D;
    float* loss_out = ind_out + NPTS;

    float*    e_sqt = (float*)d_ws;                          // 2048 f
    float*    cacc  = e_sqt + KCODES;                        // 2048 f
    _Float16* ehi   = (_Float16*)(cacc + KCODES);            // K*D halves (swizzled)
    _Float16* elo   = ehi + (size_t)KCODES * D;
    _Float16* xhi   = elo + (size_t)KCODES * D;              // N*D halves (swizzled)
    _Float16* xlo   = xhi + (size_t)NPTS * D;
    float*    pm    = (float*)(xlo + (size_t)NPTS * D);      // 2*N
    float*    pl    = pm + (size_t)A_CSLICES * NPTS;         // 2*N
    int*      pidx  = (int*)(pl + (size_t)A_CSLICES * NPTS); // 2*N

    prep_kernel<<<KCODES / 64 + NPTS / 64, 256, 0, stream>>>(
        embed, x, e_sqt, ehi, elo, xhi, xlo, cacc);
    sweepA_kernel<<<dim3(NPTS / 128, A_CSLICES), 256, 0, stream>>>(
        xhi, xlo, ehi, elo, e_sqt, pm, pl, pidx);
    sweepB_kernel<<<dim3(NPTS / 128, A_CSLICES), 256, 0, stream>>>(
        xhi, xlo, ehi, elo, e_sqt, pm, pl, pidx, cacc, embed, q_out, ind_out);
    finalize_kernel<<<1, 256, 0, stream>>>(cacc, loss_out, NPTS, KCODES);
}